// Round 6
// baseline (120.571 us; speedup 1.0000x reference)
//
#include <hip/hip_runtime.h>
#include <hip/hip_bf16.h>

__device__ __forceinline__ float bf2f(unsigned short u) {
    union { unsigned int i; float f; } v; v.i = ((unsigned int)u) << 16; return v.f;
}
__device__ __forceinline__ unsigned short f2bf(float f) {
    __hip_bfloat16 h = __float2bfloat16(f);
    return *reinterpret_cast<unsigned short*>(&h);
}

// ws layout:
//   Q  fp32 [b][g][4096][16]                      4 MB
//   K  bf16 canvas [b][g][80][80][16]             3.2768 MB  (zero-padded)
//   V  bf16 canvas [b][g][80][80][16]             3.2768 MB  (zero-padded)
// Canvas: pixel (h,w) lives at row h+8, col w+8. Pads zeroed every iter
// (harness poisons ws); conv(0)=0 == reference zero-padding semantics.

#define CANVAS_SLAB 102400   // 80*80*16 ushorts per (b,g)

// ---------------------------------------------------------------------------
// pad_zero: zero both K/V canvases with plain stores. grid 1600x256x16B.
// ---------------------------------------------------------------------------
__global__ __launch_bounds__(256) void pad_zero_kernel(uint4* __restrict__ p)
{
    const size_t i = (size_t)blockIdx.x * 256 + threadIdx.x;
    p[i] = make_uint4(0u, 0u, 0u, 0u);
}

// ---------------------------------------------------------------------------
// conv v2 (unchanged): three 1x1 convs, fp32, register-tiled GEMM.
// Block = 64 out-ch x 64 px (thread = 4 ch x 4 px), grid (128,2,3) = 768
// blocks = 3/CU. LDS: w_s + x_s 64x68 each.
// ---------------------------------------------------------------------------
__global__ __launch_bounds__(256) void conv_kernel(
    const float* __restrict__ fm,
    const float* __restrict__ wq, const float* __restrict__ wk,
    const float* __restrict__ wv,
    float* __restrict__ Qout,
    unsigned short* __restrict__ K0,
    unsigned short* __restrict__ V0)
{
    const int sel = blockIdx.z;
    const int by  = blockIdx.y;            // out-ch half (0: ch 0-63, 1: 64-127)
    const float* W = (sel == 0) ? wq : ((sel == 1) ? wk : wv);
    const int c0 = (sel == 0) ? 128 : 0;   // Q reads fm_t1, K/V read fm_t0

    __shared__ float w_s[64 * 68];    // [k][o], o stride 68
    __shared__ float x_s[64 * 68];    // [k][px], px stride 68

    const int tid = threadIdx.x;
    const int P0  = blockIdx.x * 64;  // one full row of one image
    const int b   = P0 >> 12;
    const int hw0 = P0 & 4095;

    float acc[4][4];
    #pragma unroll
    for (int i = 0; i < 4; ++i)
        #pragma unroll
        for (int j = 0; j < 4; ++j) acc[i][j] = 0.f;

    const int ocb = (tid >> 4) * 4;   // out-ch base within half (0,4,...,60)
    const int pxb = (tid & 15) * 4;   // px base (0,4,...,60)

    for (int kh = 0; kh < 128; kh += 64) {
        {
            const int o    = tid >> 2;          // 0..63
            const int koff = (tid & 3) * 16;    // 0,16,32,48
            #pragma unroll
            for (int i = 0; i < 4; ++i) {
                float4 v = *(const float4*)(W + (size_t)(by * 64 + o) * 128 + kh + koff + i * 4);
                w_s[(koff + i * 4 + 0) * 68 + o] = v.x;
                w_s[(koff + i * 4 + 1) * 68 + o] = v.y;
                w_s[(koff + i * 4 + 2) * 68 + o] = v.z;
                w_s[(koff + i * 4 + 3) * 68 + o] = v.w;
            }
        }
        {
            const int c  = tid >> 2;            // 0..63
            const int pc = (tid & 3) * 16;      // 0,16,32,48
            const float* src = fm + (((size_t)(b * 256 + c0 + kh + c)) << 12) + hw0 + pc;
            #pragma unroll
            for (int i = 0; i < 4; ++i)
                *(float4*)(&x_s[c * 68 + pc + i * 4]) = *(const float4*)(src + i * 4);
        }
        __syncthreads();
        #pragma unroll 8
        for (int k = 0; k < 64; ++k) {
            float4 wa = *(const float4*)(&w_s[k * 68 + ocb]);
            float4 xv = *(const float4*)(&x_s[k * 68 + pxb]);
            const float wf[4] = {wa.x, wa.y, wa.z, wa.w};
            const float xf[4] = {xv.x, xv.y, xv.z, xv.w};
            #pragma unroll
            for (int i = 0; i < 4; ++i)
                #pragma unroll
                for (int j = 0; j < 4; ++j) acc[i][j] += wf[i] * xf[j];
        }
        __syncthreads();
    }

    const int oc  = by * 64 + ocb;     // global out-ch base (multiple of 4)
    const int g   = oc >> 4;
    const int lci = oc & 15;           // 0,4,8,12 — stays within one group
    const int hh  = hw0 >> 6;          // row (constant per block)
    #pragma unroll
    for (int pj = 0; pj < 4; ++pj) {
        const int ww = pxb + pj;
        if (sel == 0) {
            const size_t base = ((((size_t)(b * 8 + g)) << 12) + (hh * 64 + ww)) * 16 + lci;
            *(float4*)(Qout + base) = make_float4(acc[0][pj], acc[1][pj], acc[2][pj], acc[3][pj]);
        } else {
            const size_t cbase = (size_t)(b * 8 + g) * CANVAS_SLAB
                               + ((size_t)((hh + 8) * 80 + (ww + 8))) * 16 + lci;
            unsigned short tmp[4];
            #pragma unroll
            for (int i = 0; i < 4; ++i) tmp[i] = f2bf(acc[i][pj]);
            unsigned short* dst = ((sel == 1) ? K0 : V0) + cbase;
            *(uint2*)dst = *(const uint2*)tmp;
        }
    }
}

// ---------------------------------------------------------------------------
// attn v4: LDS-staged K/V. One thread per (b,g,h,w) per PART (16 ch/thread).
// Each block stages its part's K-row window into LDS (coalesced), dots from
// LDS, syncs, re-stages V into the SAME buffer, axpy from LDS. LDS pixel
// slot = 32B (16B aligned) with XOR-swizzle of the half-slot on px bit2 so
// stride-32B wave reads hit all 8 bank groups (conflict-optimal).
// Row windows: part0 10 rows, part1 4 rows, part2 18 rows (46.08 KB max).
// block 256 = 4 rows x 64 cols; grid (16, 8, 6) with z = b*3 + part.
// ---------------------------------------------------------------------------
struct KV16 { uint4 a, b; };
__device__ __forceinline__ float dotq(const float* q, const KV16& k) {
    const unsigned short* u = (const unsigned short*)&k;
    float s = 0.f;
    #pragma unroll
    for (int c = 0; c < 16; ++c) s += q[c] * bf2f(u[c]);
    return s;
}
__device__ __forceinline__ void axpyq(float* acc, float wgt, const KV16& v) {
    const unsigned short* u = (const unsigned short*)&v;
    #pragma unroll
    for (int c = 0; c < 16; ++c) acc[c] += wgt * bf2f(u[c]);
}

// Stage NR canvas rows [R0, R0+NR) x 80 px into LDS. Slot layout (shorts):
// row*1280 + px*16 + (half ^ ((px>>2)&1))*8.  16B chunks, coalesced src.
__device__ __forceinline__ void stage_rows(unsigned short* kvs,
    const unsigned short* __restrict__ slab, int R0, int NR, int tid)
{
    const int nchunk = NR * 160;
    for (int c = tid; c < nchunk; c += 256) {
        const int row  = c / 160;
        const int rem  = c - row * 160;
        const int px   = rem >> 1;
        const int half = rem & 1;
        const uint4 v = *(const uint4*)(slab + ((size_t)(R0 + row) * 80 + px) * 16 + half * 8);
        const int dst = row * 1280 + px * 16 + ((half ^ ((px >> 2) & 1)) << 3);
        *(uint4*)(kvs + dst) = v;
    }
}
// Read the 16-ch pixel at (rowIdx, px) honoring the half swizzle.
__device__ __forceinline__ KV16 lds16(const unsigned short* kvs, int rowIdx, int px) {
    const int base = rowIdx * 1280 + px * 16;
    const int sw   = ((px >> 2) & 1) << 3;   // 0 or 8 shorts
    KV16 r;
    r.a = *(const uint4*)(kvs + base + sw);        // half 0
    r.b = *(const uint4*)(kvs + base + (8 - sw));  // half 1
    return r;
}

__global__ __launch_bounds__(256) void attn_kernel(
    const float* __restrict__ Q,
    const unsigned short* __restrict__ K0,
    const unsigned short* __restrict__ V0,
    const float* __restrict__ rel_h,
    const float* __restrict__ rel_w,
    float* __restrict__ out)
{
    const int tid  = threadIdx.x;
    const int w    = tid & 63;
    const int hr   = tid >> 6;            // row within block (0..3)
    const int h0   = blockIdx.x * 4;
    const int h    = h0 + hr;
    const int g    = blockIdx.y;
    const int b    = blockIdx.z / 3;
    const int part = blockIdx.z % 3;

    __shared__ __align__(16) unsigned short kvs[18 * 1280];  // 46.08 KB

    const size_t slabQ = ((size_t)(b * 8 + g)) << 16;
    const float* qptr = Q + slabQ + (size_t)(h * 64 + w) * 16;

    const unsigned short* Kp = K0 + (size_t)(b * 8 + g) * CANVAS_SLAB;
    const unsigned short* Vp = V0 + (size_t)(b * 8 + g) * CANVAS_SLAB;

    float qr[16];
    #pragma unroll
    for (int ci = 0; ci < 16; ++ci) qr[ci] = qptr[ci];

    float acc[16];
    #pragma unroll
    for (int ci = 0; ci < 16; ++ci) acc[ci] = 0.f;

    if (part == 0) {
        stage_rows(kvs, Kp, h0 + 5, 10, tid);
        // qrel overlaps staging (no LDS dependence)
        float qrel[7];
        const float* rel = (g < 4) ? (rel_h + g * 112) : (rel_w + (g - 4) * 112);
        #pragma unroll
        for (int t = 0; t < 7; ++t) {
            float s = 0.f;
            #pragma unroll
            for (int ci = 0; ci < 16; ++ci) s += qr[ci] * rel[ci * 7 + t];
            qrel[t] = s;
        }
        const bool bias_i = (g < 4);
        __syncthreads();

        float sc[49];
        float mx = -3.4e38f;
        #pragma unroll
        for (int i = 0; i < 7; ++i) {
            const int ri = hr + i;
            #pragma unroll
            for (int j = 0; j < 7; ++j) {
                float d = dotq(qr, lds16(kvs, ri, w + j + 5));
                d += bias_i ? qrel[i] : qrel[j];
                sc[i * 7 + j] = d;
                mx = fmaxf(mx, d);
            }
        }
        float den = 0.f;
        #pragma unroll
        for (int k = 0; k < 49; ++k) { sc[k] = __expf(sc[k] - mx); den += sc[k]; }
        const float inv = 1.f / den;

        __syncthreads();                       // all dots done before overwrite
        stage_rows(kvs, Vp, h0 + 5, 10, tid);
        __syncthreads();

        #pragma unroll
        for (int i = 0; i < 7; ++i) {
            const int ri = hr + i;
            #pragma unroll
            for (int j = 0; j < 7; ++j)
                axpyq(acc, sc[i * 7 + j] * inv, lds16(kvs, ri, w + j + 5));
        }
    } else if (part == 1) {
        stage_rows(kvs, Kp, h0 + 8, 4, tid);
        __syncthreads();

        float sc[15];
        float mx = -3.4e38f;
        #pragma unroll
        for (int j = 0; j < 15; ++j) {
            const float d = dotq(qr, lds16(kvs, hr, w + j + 1));
            sc[j] = d; mx = fmaxf(mx, d);
        }
        float den = 0.f;
        #pragma unroll
        for (int j = 0; j < 15; ++j) { sc[j] = __expf(sc[j] - mx); den += sc[j]; }
        const float inv = 1.f / den;

        __syncthreads();
        stage_rows(kvs, Vp, h0 + 8, 4, tid);
        __syncthreads();

        #pragma unroll
        for (int j = 0; j < 15; ++j)
            axpyq(acc, sc[j] * inv, lds16(kvs, hr, w + j + 1));
    } else {
        stage_rows(kvs, Kp, h0 + 1, 18, tid);
        __syncthreads();

        float sc[15];
        float mx = -3.4e38f;
        #pragma unroll
        for (int i = 0; i < 15; ++i) {
            const float d = dotq(qr, lds16(kvs, hr + i, w + 8));
            sc[i] = d; mx = fmaxf(mx, d);
        }
        float den = 0.f;
        #pragma unroll
        for (int i = 0; i < 15; ++i) { sc[i] = __expf(sc[i] - mx); den += sc[i]; }
        const float inv = 1.f / den;

        __syncthreads();
        stage_rows(kvs, Vp, h0 + 1, 18, tid);
        __syncthreads();

        #pragma unroll
        for (int i = 0; i < 15; ++i)
            axpyq(acc, sc[i] * inv, lds16(kvs, hr + i, w + 8));
    }

    // accumulate: out[b][g*16+ci][h][w] += acc[ci]
    float* op = out + (((size_t)(b * 128 + g * 16)) << 12) + h * 64 + w;
    #pragma unroll
    for (int ci = 0; ci < 16; ++ci)
        atomicAdd(op + ((size_t)ci << 12), acc[ci]);
}

// ---------------------------------------------------------------------------
extern "C" void kernel_launch(void* const* d_in, const int* in_sizes, int n_in,
                              void* d_out, int out_size, void* d_ws, size_t ws_size,
                              hipStream_t stream) {
    (void)in_sizes; (void)n_in; (void)ws_size;
    const float* fm    = (const float*)d_in[0];
    const float* wq    = (const float*)d_in[1];
    const float* wk    = (const float*)d_in[2];
    const float* wv    = (const float*)d_in[3];
    const float* rel_h = (const float*)d_in[4];
    const float* rel_w = (const float*)d_in[5];

    float* Q = (float*)d_ws;                               // 1048576 floats (4 MB)
    unsigned short* K0 = (unsigned short*)(Q + 1048576);   // 16*102400 ushorts
    unsigned short* V0 = K0 + 16 * CANVAS_SLAB;            // 16*102400 ushorts

    hipMemsetAsync(d_out, 0, (size_t)out_size * sizeof(float), stream);
    pad_zero_kernel<<<dim3(1600), dim3(256), 0, stream>>>((uint4*)K0);

    conv_kernel<<<dim3(128, 2, 3), dim3(256), 0, stream>>>(
        fm, wq, wk, wv, Q, K0, V0);
    attn_kernel<<<dim3(16, 8, 6), dim3(256), 0, stream>>>(
        Q, K0, V0, rel_h, rel_w, (float*)d_out);
}

// Round 7
// 109.064 us; speedup vs baseline: 1.1055x; 1.1055x over previous
//
#include <hip/hip_runtime.h>
#include <hip/hip_bf16.h>

__device__ __forceinline__ float bf2f(unsigned short u) {
    union { unsigned int i; float f; } v; v.i = ((unsigned int)u) << 16; return v.f;
}
__device__ __forceinline__ unsigned short f2bf(float f) {
    __hip_bfloat16 h = __float2bfloat16(f);
    return *reinterpret_cast<unsigned short*>(&h);
}

// ws layout:
//   Q  fp32 [b][g][4096][16]                      4 MB
//   K  bf16 canvas [b][g][80][80][16]             3.2768 MB  (zero-padded)
//   V  bf16 canvas [b][g][80][80][16]             3.2768 MB  (zero-padded)
//   P  fp32 [part][b][128][4096]                  12 MB (per-part partials)
// Canvas: pixel (h,w) lives at row h+8, col w+8. Pads zeroed every iter.

#define CANVAS_SLAB 102400   // 80*80*16 ushorts per (b,g)

// ---------------------------------------------------------------------------
// pad_zero: zero both K/V canvases with plain stores. grid 1600x256x16B.
// ---------------------------------------------------------------------------
__global__ __launch_bounds__(256) void pad_zero_kernel(uint4* __restrict__ p)
{
    const size_t i = (size_t)blockIdx.x * 256 + threadIdx.x;
    p[i] = make_uint4(0u, 0u, 0u, 0u);
}

// ---------------------------------------------------------------------------
// conv v2 (unchanged): three 1x1 convs, fp32, register-tiled GEMM.
// Block = 64 out-ch x 64 px (thread = 4 ch x 4 px), grid (128,2,3) = 768
// blocks = 3/CU. LDS: w_s + x_s 64x68 each.
// ---------------------------------------------------------------------------
__global__ __launch_bounds__(256) void conv_kernel(
    const float* __restrict__ fm,
    const float* __restrict__ wq, const float* __restrict__ wk,
    const float* __restrict__ wv,
    float* __restrict__ Qout,
    unsigned short* __restrict__ K0,
    unsigned short* __restrict__ V0)
{
    const int sel = blockIdx.z;
    const int by  = blockIdx.y;            // out-ch half (0: ch 0-63, 1: 64-127)
    const float* W = (sel == 0) ? wq : ((sel == 1) ? wk : wv);
    const int c0 = (sel == 0) ? 128 : 0;   // Q reads fm_t1, K/V read fm_t0

    __shared__ float w_s[64 * 68];    // [k][o], o stride 68
    __shared__ float x_s[64 * 68];    // [k][px], px stride 68

    const int tid = threadIdx.x;
    const int P0  = blockIdx.x * 64;  // one full row of one image
    const int b   = P0 >> 12;
    const int hw0 = P0 & 4095;

    float acc[4][4];
    #pragma unroll
    for (int i = 0; i < 4; ++i)
        #pragma unroll
        for (int j = 0; j < 4; ++j) acc[i][j] = 0.f;

    const int ocb = (tid >> 4) * 4;   // out-ch base within half (0,4,...,60)
    const int pxb = (tid & 15) * 4;   // px base (0,4,...,60)

    for (int kh = 0; kh < 128; kh += 64) {
        {
            const int o    = tid >> 2;          // 0..63
            const int koff = (tid & 3) * 16;    // 0,16,32,48
            #pragma unroll
            for (int i = 0; i < 4; ++i) {
                float4 v = *(const float4*)(W + (size_t)(by * 64 + o) * 128 + kh + koff + i * 4);
                w_s[(koff + i * 4 + 0) * 68 + o] = v.x;
                w_s[(koff + i * 4 + 1) * 68 + o] = v.y;
                w_s[(koff + i * 4 + 2) * 68 + o] = v.z;
                w_s[(koff + i * 4 + 3) * 68 + o] = v.w;
            }
        }
        {
            const int c  = tid >> 2;            // 0..63
            const int pc = (tid & 3) * 16;      // 0,16,32,48
            const float* src = fm + (((size_t)(b * 256 + c0 + kh + c)) << 12) + hw0 + pc;
            #pragma unroll
            for (int i = 0; i < 4; ++i)
                *(float4*)(&x_s[c * 68 + pc + i * 4]) = *(const float4*)(src + i * 4);
        }
        __syncthreads();
        #pragma unroll 8
        for (int k = 0; k < 64; ++k) {
            float4 wa = *(const float4*)(&w_s[k * 68 + ocb]);
            float4 xv = *(const float4*)(&x_s[k * 68 + pxb]);
            const float wf[4] = {wa.x, wa.y, wa.z, wa.w};
            const float xf[4] = {xv.x, xv.y, xv.z, xv.w};
            #pragma unroll
            for (int i = 0; i < 4; ++i)
                #pragma unroll
                for (int j = 0; j < 4; ++j) acc[i][j] += wf[i] * xf[j];
        }
        __syncthreads();
    }

    const int oc  = by * 64 + ocb;     // global out-ch base (multiple of 4)
    const int g   = oc >> 4;
    const int lci = oc & 15;           // 0,4,8,12 — stays within one group
    const int hh  = hw0 >> 6;          // row (constant per block)
    #pragma unroll
    for (int pj = 0; pj < 4; ++pj) {
        const int ww = pxb + pj;
        if (sel == 0) {
            const size_t base = ((((size_t)(b * 8 + g)) << 12) + (hh * 64 + ww)) * 16 + lci;
            *(float4*)(Qout + base) = make_float4(acc[0][pj], acc[1][pj], acc[2][pj], acc[3][pj]);
        } else {
            const size_t cbase = (size_t)(b * 8 + g) * CANVAS_SLAB
                               + ((size_t)((hh + 8) * 80 + (ww + 8))) * 16 + lci;
            unsigned short tmp[4];
            #pragma unroll
            for (int i = 0; i < 4; ++i) tmp[i] = f2bf(acc[i][pj]);
            unsigned short* dst = ((sel == 1) ? K0 : V0) + cbase;
            *(uint2*)dst = *(const uint2*)tmp;
        }
    }
}

// ---------------------------------------------------------------------------
// attn v5: = v3 (global loads from zero-padded canvas, 16 ch/thread, no
// bounds checks) BUT plain coalesced stores into a per-part partial buffer
// P[part][b][128][4096] instead of 16 atomicAdds into out. No memset(out).
// block 256 = 4 rows x 64 cols; grid (16, 8, 6) with z = b*3 + part.
// ---------------------------------------------------------------------------
struct KV16 { uint4 a, b; };
__device__ __forceinline__ KV16 ld16(const unsigned short* p) {
    KV16 r; r.a = *(const uint4*)p; r.b = *(const uint4*)(p + 8); return r;
}
__device__ __forceinline__ float dotq(const float* q, const KV16& k) {
    const unsigned short* u = (const unsigned short*)&k;
    float s = 0.f;
    #pragma unroll
    for (int c = 0; c < 16; ++c) s += q[c] * bf2f(u[c]);
    return s;
}
__device__ __forceinline__ void axpyq(float* acc, float wgt, const KV16& v) {
    const unsigned short* u = (const unsigned short*)&v;
    #pragma unroll
    for (int c = 0; c < 16; ++c) acc[c] += wgt * bf2f(u[c]);
}

__global__ __launch_bounds__(256) void attn_kernel(
    const float* __restrict__ Q,
    const unsigned short* __restrict__ K0,
    const unsigned short* __restrict__ V0,
    const float* __restrict__ rel_h,
    const float* __restrict__ rel_w,
    float* __restrict__ P)
{
    const int tid  = threadIdx.x;
    const int w    = tid & 63;
    const int h    = blockIdx.x * 4 + (tid >> 6);
    const int g    = blockIdx.y;
    const int b    = blockIdx.z / 3;
    const int part = blockIdx.z % 3;

    const size_t slabQ = ((size_t)(b * 8 + g)) << 16;
    const float* qptr = Q + slabQ + (size_t)(h * 64 + w) * 16;

    float qr[16];
    #pragma unroll
    for (int ci = 0; ci < 16; ++ci) qr[ci] = qptr[ci];

    const unsigned short* Kp = K0 + (size_t)(b * 8 + g) * CANVAS_SLAB;
    const unsigned short* Vp = V0 + (size_t)(b * 8 + g) * CANVAS_SLAB;

    // canvas element index for pixel (y, x), y/x may be in [-8, 71]
    #define CIDX(y, x) (((size_t)(((y) + 8) * 80 + ((x) + 8))) << 4)

    float acc[16];
    #pragma unroll
    for (int ci = 0; ci < 16; ++ci) acc[ci] = 0.f;

    if (part == 0) {
        // qrel[t] = q . rel[:,t]; rel_h for g<4 (depends on i), rel_w else (j)
        float qrel[7];
        const float* rel = (g < 4) ? (rel_h + g * 112) : (rel_w + (g - 4) * 112);
        #pragma unroll
        for (int t = 0; t < 7; ++t) {
            float s = 0.f;
            #pragma unroll
            for (int ci = 0; ci < 16; ++ci) s += qr[ci] * rel[ci * 7 + t];
            qrel[t] = s;
        }
        const bool bias_i = (g < 4);
        float sc[49];
        float mx = -3.4e38f;
        #pragma unroll
        for (int i = 0; i < 7; ++i) {
            const int y = h + i - 3;
            #pragma unroll
            for (int j = 0; j < 7; ++j) {
                const int x = w + j - 3;
                float d = dotq(qr, ld16(Kp + CIDX(y, x)));
                d += bias_i ? qrel[i] : qrel[j];
                sc[i * 7 + j] = d;
                mx = fmaxf(mx, d);
            }
        }
        float den = 0.f;
        #pragma unroll
        for (int k = 0; k < 49; ++k) { sc[k] = __expf(sc[k] - mx); den += sc[k]; }
        const float inv = 1.f / den;
        #pragma unroll
        for (int i = 0; i < 7; ++i) {
            const int y = h + i - 3;
            #pragma unroll
            for (int j = 0; j < 7; ++j) {
                const int x = w + j - 3;
                axpyq(acc, sc[i * 7 + j] * inv, ld16(Vp + CIDX(y, x)));
            }
        }
    } else if (part == 1) {
        // refine row (w offsets)
        float sc[15];
        float mx = -3.4e38f;
        #pragma unroll
        for (int j = 0; j < 15; ++j) {
            const int x = w + j - 7;
            const float d = dotq(qr, ld16(Kp + CIDX(h, x)));
            sc[j] = d; mx = fmaxf(mx, d);
        }
        float den = 0.f;
        #pragma unroll
        for (int j = 0; j < 15; ++j) { sc[j] = __expf(sc[j] - mx); den += sc[j]; }
        const float inv = 1.f / den;
        #pragma unroll
        for (int j = 0; j < 15; ++j) {
            const int x = w + j - 7;
            axpyq(acc, sc[j] * inv, ld16(Vp + CIDX(h, x)));
        }
    } else {
        // refine col (h offsets)
        float sc[15];
        float mx = -3.4e38f;
        #pragma unroll
        for (int i = 0; i < 15; ++i) {
            const int y = h + i - 7;
            const float d = dotq(qr, ld16(Kp + CIDX(y, w)));
            sc[i] = d; mx = fmaxf(mx, d);
        }
        float den = 0.f;
        #pragma unroll
        for (int i = 0; i < 15; ++i) { sc[i] = __expf(sc[i] - mx); den += sc[i]; }
        const float inv = 1.f / den;
        #pragma unroll
        for (int i = 0; i < 15; ++i) {
            const int y = h + i - 7;
            axpyq(acc, sc[i] * inv, ld16(Vp + CIDX(y, w)));
        }
    }
    #undef CIDX

    // plain coalesced stores: P[part][b][g*16+ci][h][w] = acc[ci]
    float* op = P + ((((size_t)part * 2 + b) * 128 + g * 16) << 12) + h * 64 + w;
    #pragma unroll
    for (int ci = 0; ci < 16; ++ci)
        op[(size_t)ci << 12] = acc[ci];
}

// ---------------------------------------------------------------------------
// combine: out = P0 + P1 + P2, float4 grid-stride-free exact sizing.
// 1,048,576 floats = 262,144 float4 -> 1024 blocks x 256 threads.
// ---------------------------------------------------------------------------
__global__ __launch_bounds__(256) void combine_kernel(
    const float4* __restrict__ P, float4* __restrict__ out)
{
    const size_t i = (size_t)blockIdx.x * 256 + threadIdx.x;
    const float4 a = P[i];
    const float4 c = P[i + 262144];
    const float4 d = P[i + 524288];
    out[i] = make_float4(a.x + c.x + d.x, a.y + c.y + d.y,
                         a.z + c.z + d.z, a.w + c.w + d.w);
}

// ---------------------------------------------------------------------------
extern "C" void kernel_launch(void* const* d_in, const int* in_sizes, int n_in,
                              void* d_out, int out_size, void* d_ws, size_t ws_size,
                              hipStream_t stream) {
    (void)in_sizes; (void)n_in; (void)ws_size; (void)out_size;
    const float* fm    = (const float*)d_in[0];
    const float* wq    = (const float*)d_in[1];
    const float* wk    = (const float*)d_in[2];
    const float* wv    = (const float*)d_in[3];
    const float* rel_h = (const float*)d_in[4];
    const float* rel_w = (const float*)d_in[5];

    float* Q = (float*)d_ws;                               // 1048576 floats (4 MB)
    unsigned short* K0 = (unsigned short*)(Q + 1048576);   // 16*102400 ushorts
    unsigned short* V0 = K0 + 16 * CANVAS_SLAB;            // 16*102400 ushorts
    float* P = (float*)(V0 + 16 * CANVAS_SLAB);            // 3*1048576 floats (12 MB)

    pad_zero_kernel<<<dim3(1600), dim3(256), 0, stream>>>((uint4*)K0);

    conv_kernel<<<dim3(128, 2, 3), dim3(256), 0, stream>>>(
        fm, wq, wk, wv, Q, K0, V0);
    attn_kernel<<<dim3(16, 8, 6), dim3(256), 0, stream>>>(
        Q, K0, V0, rel_h, rel_w, P);
    combine_kernel<<<dim3(1024), dim3(256), 0, stream>>>(
        (const float4*)P, (float4*)d_out);
}